// Round 16
// baseline (412.579 us; speedup 1.0000x reference)
//
#include <hip/hip_runtime.h>
#include <stdint.h>

typedef unsigned short u16;
typedef short bf16x8 __attribute__((ext_vector_type(8)));
typedef float f32x4 __attribute__((ext_vector_type(4)));
typedef u16 u16x4 __attribute__((ext_vector_type(4)));

__device__ __forceinline__ u16 f2bf(float f) {
    unsigned u = __builtin_bit_cast(unsigned, f);
    unsigned r = (u + 0x7fffu + ((u >> 16) & 1u)) >> 16;
    return (u16)r;
}
__device__ __forceinline__ float bf2f(u16 h) {
    unsigned u = ((unsigned)h) << 16;
    return __builtin_bit_cast(float, u);
}

typedef const __attribute__((address_space(1))) unsigned int* gptr_t;
typedef __attribute__((address_space(3))) unsigned int* lptr_t;
__device__ __forceinline__ void gload16(const void* g, void* l) {
    __builtin_amdgcn_global_load_lds((gptr_t)(uintptr_t)g, (lptr_t)(uintptr_t)l, 16, 0, 0);
}

// branch tables: rows of the concatenated 960-row score/Q space
__device__ __constant__ int d_offs[4] = {0, 512, 768, 896};
__device__ __constant__ int d_cs[4] = {512, 256, 128, 64};

// ---------------- single cast (fallback path) ----------------
__global__ __launch_bounds__(256) void cast_bf16(const float4* __restrict__ in,
                                                 u16x4* __restrict__ out, int n4) {
    int i = blockIdx.x * 256 + threadIdx.x;
    if (i < n4) {
        float4 f = in[i];
        u16x4 o = {f2bf(f.x), f2bf(f.y), f2bf(f.z), f2bf(f.w)};
        out[i] = o;
    }
}

// ---------------- multi-segment cast: one launch for all f32->bf16 ----------------
struct CastPack {
    const float4* src[15];
    u16x4* dst[15];
    int n4[15];
    int cum[16];
    int nseg;
};
__global__ __launch_bounds__(256) void cast_multi(CastPack p) {
    int b = blockIdx.x, t = threadIdx.x;
    int s = 0;
    while (s + 1 < p.nseg && b >= p.cum[s + 1]) s++;
    int lb = b - p.cum[s], nb = p.cum[s + 1] - p.cum[s];
    const float4* src = p.src[s];
    u16x4* dst = p.dst[s];
    int n4 = p.n4[s];
    for (int i = lb * 256 + t; i < n4; i += nb * 256) {
        float4 f = src[i];
        u16x4 o = {f2bf(f.x), f2bf(f.y), f2bf(f.z), f2bf(f.w)};
        dst[i] = o;
    }
}

// ======== 2-phase-per-K-tile NT GEMM, BK-templated (r16: BK=32, bounds(512,2)) ========
// r13-proven schedule; BK=32 -> 64KiB LDS -> 2 blocks/CU IF natural VGPR <= 128
// (r14's failure was __launch_bounds__(512,4) forcing 64-VGPR spill, not BK=32 itself;
// r14 passed correctness). Allocator left free here.
#define ARDH(DST, BUFO, H)                                                          \
    _Pragma("unroll") for (int f = 0; f < HMF; f++)                                 \
        _Pragma("unroll") for (int kb = 0; kb < KB; kb++) {                         \
            int rl = ((H)*HMF + f) * 16 + la;                                       \
            int sl = kb * 4 + lk4;                                                  \
            DST[f][kb] = *(const bf16x8*)&lds[(BUFO) + rl * BK +                    \
                                              (((sl ^ (rl & (SL - 1)))) << 3)];     \
        }
#define BRD(BUFO)                                                                   \
    _Pragma("unroll") for (int ni = 0; ni < 4; ni++)                                \
        _Pragma("unroll") for (int kb = 0; kb < KB; kb++) {                         \
            int rl = brow0 + ni * 16 + la;                                          \
            int sl = kb * 4 + lk4;                                                  \
            breg[ni][kb] = *(const bf16x8*)&lds[(BUFO) + rl * BK +                  \
                                                (((sl ^ (rl & (SL - 1)))) << 3)];   \
        }
#define MMAH(H, SRC)                                                                \
    __builtin_amdgcn_sched_barrier(0);                                              \
    __builtin_amdgcn_s_setprio(1);                                                  \
    _Pragma("unroll") for (int f = 0; f < HMF; f++)                                 \
        _Pragma("unroll") for (int ni = 0; ni < 4; ni++)                            \
            _Pragma("unroll") for (int kb = 0; kb < KB; kb++)                       \
                acc[(H)*HMF + f][ni] = __builtin_amdgcn_mfma_f32_16x16x32_bf16(     \
                    SRC[f][kb], breg[ni][kb], acc[(H)*HMF + f][ni], 0, 0, 0);       \
    __builtin_amdgcn_s_setprio(0);
#define WLG0 asm volatile("s_waitcnt lgkmcnt(0)" ::: "memory")

template <int BM, int BK>
__global__ __launch_bounds__(512, 2) void gemm_nt_4ph(
    const u16* __restrict__ A, long sAb, long sAh, int lda,
    const u16* __restrict__ B, long sBb, long sBh, int ldb,
    u16* __restrict__ C, long sCb, long sCh, int ldc,
    int M, int N, int K, int hdiv, float alpha) {
    constexpr int KB = BK / 32;                // K32 blocks per tile
    constexpr int SL = BK / 8;                 // 16B slots per row
    constexpr int WTM = BM / 2;                // per-wave rows
    constexpr int NMF = WTM / 16;              // m-frags per wave
    constexpr int HMF = NMF / 2;               // m-frags per half-phase
    constexpr int NA = WTM * BK / 4096;        // gloads per thread per A-half
    constexpr int NB = 128 * BK / 4096;        // gloads per thread per B-half
    constexpr int APART = WTM * BK;
    constexpr int BPART = 128 * BK;
    constexpr int BUFSZ = 2 * APART + 2 * BPART;
    constexpr int AHC = HMF * KB;              // aHi read count (counted lgkm)
    __shared__ u16 lds[2 * BUFSZ];

    // bijective XCD swizzle (m204)
    int gx = gridDim.x, gy = gridDim.y;
    int nwg = gx * gy * gridDim.z;
    int orig = blockIdx.x + gx * (blockIdx.y + gy * blockIdx.z);
    int q = nwg >> 3, r = nwg & 7;
    int xcd = orig & 7, seq = orig >> 3;
    int wg = (xcd < r ? xcd * (q + 1) : r * (q + 1) + (xcd - r) * q) + seq;
    int bx = wg % gx, tmpw = wg / gx;
    int by = tmpw % gy, bz = tmpw / gy;

    int bb = bz / hdiv, hh = bz - bb * hdiv;
    const u16* Ab = A + (size_t)bb * sAb + (size_t)hh * sAh;
    const u16* Bb = B + (size_t)bb * sBb + (size_t)hh * sBh;
    u16* Cb = C + (size_t)bb * sCb + (size_t)hh * sCh;
    int tm = by * BM, tn = bx * 256;
    int t = threadIdx.x, lane = t & 63, w = t >> 6;
    int wm = w >> 2, wn = w & 3;
    int la = lane & 15, lk4 = lane >> 4;
    int brow0 = (wn & 1) * 64;

    // staging source pointers: inverse-swizzled col, clamped rows; += BK per tile
    const u16* pA0[NA];
    const u16* pA1[NA];
    const u16* pB0[NB];
    const u16* pB1[NB];
#pragma unroll
    for (int i = 0; i < NA; i++) {
        int seg = i * 512 + t;
        int row = seg / SL, slot = seg % SL;
        int col = ((slot ^ (row & (SL - 1))) << 3);
        int r0 = tm + row;
        if (r0 > M - 1) r0 = M - 1;
        pA0[i] = Ab + (size_t)r0 * lda + col;
        int r1 = tm + WTM + row;
        if (r1 > M - 1) r1 = M - 1;
        pA1[i] = Ab + (size_t)r1 * lda + col;
    }
#pragma unroll
    for (int i = 0; i < NB; i++) {
        int seg = i * 512 + t;
        int row = seg / SL, slot = seg % SL;
        int col = ((slot ^ (row & (SL - 1))) << 3);
        int r0 = tn + row;
        if (r0 > N - 1) r0 = N - 1;
        pB0[i] = Bb + (size_t)r0 * ldb + col;
        int r1 = tn + 128 + row;
        if (r1 > N - 1) r1 = N - 1;
        pB1[i] = Bb + (size_t)r1 * ldb + col;
    }

    auto AOF = [&](int buf, int h) { return buf * BUFSZ + h * APART; };
    auto BOF = [&](int buf, int h) { return buf * BUFSZ + 2 * APART + h * BPART; };
    auto stA0 = [&](int buf) {
#pragma unroll
        for (int i = 0; i < NA; i++) {
            gload16(pA0[i], &lds[AOF(buf, 0) + (i * 512 + t) * 8]);
            pA0[i] += BK;
        }
    };
    auto stA1 = [&](int buf) {
#pragma unroll
        for (int i = 0; i < NA; i++) {
            gload16(pA1[i], &lds[AOF(buf, 1) + (i * 512 + t) * 8]);
            pA1[i] += BK;
        }
    };
    auto stB0 = [&](int buf) {
#pragma unroll
        for (int i = 0; i < NB; i++) {
            gload16(pB0[i], &lds[BOF(buf, 0) + (i * 512 + t) * 8]);
            pB0[i] += BK;
        }
    };
    auto stB1 = [&](int buf) {
#pragma unroll
        for (int i = 0; i < NB; i++) {
            gload16(pB1[i], &lds[BOF(buf, 1) + (i * 512 + t) * 8]);
            pB1[i] += BK;
        }
    };

    int nt = K / BK;
    stA0(0);
    stA1(0);
    stB0(0);
    stB1(0);
    if (nt > 1) {
        stB0(1);
        stB1(1);
        if constexpr (2 * NB == 4)
            asm volatile("s_waitcnt vmcnt(4)" ::: "memory");
        else
            asm volatile("s_waitcnt vmcnt(2)" ::: "memory");
    } else {
        asm volatile("s_waitcnt vmcnt(0)" ::: "memory");
    }
    __builtin_amdgcn_s_barrier();

    f32x4 acc[NMF][4] = {};
    bf16x8 breg[4][KB];
    bf16x8 aLo[HMF][KB], aHi[HMF][KB];

    for (int k = 0; k < nt; ++k) {
        int buf = k & 1, nbuf = buf ^ 1;
        int ao = AOF(buf, wm), bo = BOF(buf, wn >> 1);
        bool s1 = (k + 1 < nt), s2 = (k + 2 < nt);
        // p0: B + A-lo reads; stage A(k+1); MFMA-lo (no barrier needed)
        BRD(bo)
        ARDH(aLo, ao, 0)
        if (s1) {
            stA0(nbuf);
            stA1(nbuf);
        }
        WLG0;
        MMAH(0, aLo)
        // p1: A-hi reads; barrier; stage B(k+2) into dead slots; MFMA-hi; publish
        ARDH(aHi, ao, 1)
        __builtin_amdgcn_s_barrier();  // all waves' p0 lgkm(0) done -> B slots dead
        if (s2) {
            stB0(buf);
            stB1(buf);
        }
        WLG0;
        MMAH(1, aHi)
        if (s2) {
            if constexpr (2 * NB == 4)
                asm volatile("s_waitcnt vmcnt(4)" ::: "memory");
            else
                asm volatile("s_waitcnt vmcnt(2)" ::: "memory");
        } else {
            asm volatile("s_waitcnt vmcnt(0)" ::: "memory");
        }
        __builtin_amdgcn_s_barrier();  // publish buf[k+1] DMA
    }
    (void)AHC;
#pragma unroll
    for (int mi = 0; mi < NMF; mi++)
#pragma unroll
        for (int ni = 0; ni < 4; ni++)
#pragma unroll
            for (int r_ = 0; r_ < 4; r_++) {
                int m = tm + wm * WTM + mi * 16 + ((lane >> 4) << 2) + r_;
                int n = tn + wn * 64 + ni * 16 + la;
                if (m < M && n < N)
                    Cb[(size_t)m * ldc + n] = f2bf(acc[mi][ni][r_] * alpha);
            }
}

// ---------------- NT GEMM (m97 1-phase, 128 tile), plain (fallback) ----------------
template <typename OUT>
__global__ __launch_bounds__(256) void gemm_nt128(
    const u16* __restrict__ A, long sAb, long sAh, int lda,
    const u16* __restrict__ B, long sBb, long sBh, int ldb,
    OUT* __restrict__ C, long sCb, long sCh, int ldc,
    int M, int N, int K, int hdiv, float alpha) {
    __shared__ u16 sA[128 * 64];
    __shared__ u16 sB[128 * 64];
    int gx = gridDim.x, gy = gridDim.y;
    int nwg = gx * gy * gridDim.z;
    int orig = blockIdx.x + gx * (blockIdx.y + gy * blockIdx.z);
    int q = nwg >> 3, r = nwg & 7;
    int xcd = orig & 7, seq = orig >> 3;
    int wg = (xcd < r ? xcd * (q + 1) : r * (q + 1) + (xcd - r) * q) + seq;
    int bx = wg % gx, tmpw = wg / gx;
    int by = tmpw % gy, bz = tmpw / gy;

    int bb = bz / hdiv, hh = bz - bb * hdiv;
    const u16* Ab = A + (size_t)bb * sAb + (size_t)hh * sAh;
    const u16* Bb = B + (size_t)bb * sBb + (size_t)hh * sBh;
    OUT* Cb = C + (size_t)bb * sCb + (size_t)hh * sCh;
    int tm = by * 128, tn = bx * 128;
    int t = threadIdx.x, lane = t & 63, w = t >> 6;
    int wr = w >> 1, wc = w & 1;
    int r0 = t >> 3, c0 = (t & 7) * 8;
    const u16* gA[4];
    const u16* gB[4];
#pragma unroll
    for (int i = 0; i < 4; i++) {
        int ar = tm + i * 32 + r0;
        if (ar > M - 1) ar = M - 1;
        gA[i] = Ab + (size_t)ar * lda + c0;
    }
#pragma unroll
    for (int i = 0; i < 4; i++) {
        int br = tn + i * 32 + r0;
        if (br > N - 1) br = N - 1;
        gB[i] = Bb + (size_t)br * ldb + c0;
    }
    f32x4 acc[4][4] = {};
    int la = lane & 15, lk = (lane >> 4) * 8;
    for (int k0 = 0; k0 < K; k0 += 64) {
#pragma unroll
        for (int i = 0; i < 4; i++) {
            gload16(gA[i], &sA[(i * 256 + t) * 8]);
            gA[i] += 64;
        }
#pragma unroll
        for (int i = 0; i < 4; i++) {
            gload16(gB[i], &sB[(i * 256 + t) * 8]);
            gB[i] += 64;
        }
        __syncthreads();
#pragma unroll
        for (int kk = 0; kk < 64; kk += 32) {
            bf16x8 a[4], b[4];
#pragma unroll
            for (int mi = 0; mi < 4; mi++)
                a[mi] = *(const bf16x8*)&sA[(wr * 64 + mi * 16 + la) * 64 + kk + lk];
#pragma unroll
            for (int ni = 0; ni < 4; ni++)
                b[ni] = *(const bf16x8*)&sB[(wc * 64 + ni * 16 + la) * 64 + kk + lk];
#pragma unroll
            for (int mi = 0; mi < 4; mi++)
#pragma unroll
                for (int ni = 0; ni < 4; ni++)
                    acc[mi][ni] = __builtin_amdgcn_mfma_f32_16x16x32_bf16(
                        a[mi], b[ni], acc[mi][ni], 0, 0, 0);
        }
        __syncthreads();
    }
#pragma unroll
    for (int mi = 0; mi < 4; mi++)
#pragma unroll
        for (int ni = 0; ni < 4; ni++)
#pragma unroll
            for (int r_ = 0; r_ < 4; r_++) {
                int m = tm + wr * 64 + mi * 16 + (lane >> 4) * 4 + r_;
                int n = tn + wc * 64 + ni * 16 + la;
                if (m < M && n < N) {
                    float v = acc[mi][ni][r_] * alpha;
                    if constexpr (sizeof(OUT) == 4)
                        Cb[(size_t)m * ldc + n] = v;
                    else
                        Cb[(size_t)m * ldc + n] = f2bf(v);
                }
            }
}

// ---------------- grouped 128-tile NT GEMM: several segments in one launch ----------------
struct GSeg {
    const u16* A; long sAb, sAh; int lda;
    const u16* B; long sBb, sBh; int ldb;
    void* Cp; long sCb, sCh; int ldc;
    int M, N, K, hdiv, gx, gy, isF32;
    float alpha;
};
struct GPack {
    GSeg s[4];
    int cum[5];
    int nseg;
};
__global__ __launch_bounds__(256) void gemm_nt128_grp(GPack p) {
    int nwg = p.cum[p.nseg];
    int orig = blockIdx.x;
    int q = nwg >> 3, r = nwg & 7;
    int xcd = orig & 7, seq = orig >> 3;
    int wg = (xcd < r ? xcd * (q + 1) : r * (q + 1) + (xcd - r) * q) + seq;
    int s = 0;
    while (s + 1 < p.nseg && wg >= p.cum[s + 1]) s++;
    GSeg g;
    if (s == 0) g = p.s[0];
    else if (s == 1) g = p.s[1];
    else if (s == 2) g = p.s[2];
    else g = p.s[3];
    int lm = wg - p.cum[s];
    int bx = lm % g.gx;
    int rest = lm / g.gx;
    int by = rest % g.gy, bz = rest / g.gy;

    __shared__ u16 sA[128 * 64];
    __shared__ u16 sB[128 * 64];
    int bb = bz / g.hdiv, hh = bz - bb * g.hdiv;
    const u16* Ab = g.A + (size_t)bb * g.sAb + (size_t)hh * g.sAh;
    const u16* Bb = g.B + (size_t)bb * g.sBb + (size_t)hh * g.sBh;
    int tm = by * 128, tn = bx * 128;
    int t = threadIdx.x, lane = t & 63, w = t >> 6;
    int wr = w >> 1, wc = w & 1;
    int r0 = t >> 3, c0 = (t & 7) * 8;
    const u16* gA[4];
    const u16* gB[4];
#pragma unroll
    for (int i = 0; i < 4; i++) {
        int ar = tm + i * 32 + r0;
        if (ar > g.M - 1) ar = g.M - 1;
        gA[i] = Ab + (size_t)ar * g.lda + c0;
    }
#pragma unroll
    for (int i = 0; i < 4; i++) {
        int br = tn + i * 32 + r0;
        if (br > g.N - 1) br = g.N - 1;
        gB[i] = Bb + (size_t)br * g.ldb + c0;
    }
    f32x4 acc[4][4] = {};
    int la = lane & 15, lk = (lane >> 4) * 8;
    for (int k0 = 0; k0 < g.K; k0 += 64) {
#pragma unroll
        for (int i = 0; i < 4; i++) {
            gload16(gA[i], &sA[(i * 256 + t) * 8]);
            gA[i] += 64;
        }
#pragma unroll
        for (int i = 0; i < 4; i++) {
            gload16(gB[i], &sB[(i * 256 + t) * 8]);
            gB[i] += 64;
        }
        __syncthreads();
#pragma unroll
        for (int kk = 0; kk < 64; kk += 32) {
            bf16x8 a[4], b[4];
#pragma unroll
            for (int mi = 0; mi < 4; mi++)
                a[mi] = *(const bf16x8*)&sA[(wr * 64 + mi * 16 + la) * 64 + kk + lk];
#pragma unroll
            for (int ni = 0; ni < 4; ni++)
                b[ni] = *(const bf16x8*)&sB[(wc * 64 + ni * 16 + la) * 64 + kk + lk];
#pragma unroll
            for (int mi = 0; mi < 4; mi++)
#pragma unroll
                for (int ni = 0; ni < 4; ni++)
                    acc[mi][ni] = __builtin_amdgcn_mfma_f32_16x16x32_bf16(
                        a[mi], b[ni], acc[mi][ni], 0, 0, 0);
        }
        __syncthreads();
    }
    if (g.isF32) {
        float* Cb = (float*)g.Cp + (size_t)bb * g.sCb + (size_t)hh * g.sCh;
#pragma unroll
        for (int mi = 0; mi < 4; mi++)
#pragma unroll
            for (int ni = 0; ni < 4; ni++)
#pragma unroll
                for (int r_ = 0; r_ < 4; r_++) {
                    int m = tm + wr * 64 + mi * 16 + (lane >> 4) * 4 + r_;
                    int n = tn + wc * 64 + ni * 16 + la;
                    if (m < g.M && n < g.N)
                        Cb[(size_t)m * g.ldc + n] = acc[mi][ni][r_] * g.alpha;
                }
    } else {
        u16* Cb = (u16*)g.Cp + (size_t)bb * g.sCb + (size_t)hh * g.sCh;
#pragma unroll
        for (int mi = 0; mi < 4; mi++)
#pragma unroll
            for (int ni = 0; ni < 4; ni++)
#pragma unroll
                for (int r_ = 0; r_ < 4; r_++) {
                    int m = tm + wr * 64 + mi * 16 + (lane >> 4) * 4 + r_;
                    int n = tn + wc * 64 + ni * 16 + la;
                    if (m < g.M && n < g.N)
                        Cb[(size_t)m * g.ldc + n] = f2bf(acc[mi][ni][r_] * g.alpha);
                }
    }
}

// ---------------- instance-norm stats, stage 1 (bf16 input, two-stage deterministic) ----------------
__global__ __launch_bounds__(256) void in_stats1(const u16* __restrict__ sc,
                                                 double* __restrict__ part,
                                                 int G, int mode, int C) {
    int p = blockIdx.y, g = blockIdx.x, t = threadIdx.x;
    size_t base;
    int n8;
    if (mode) {
        int z = p >> 2, i = p & 3;
        base = (size_t)z * 921600 + (size_t)d_offs[i] * 960;
        n8 = d_cs[i] * 120;
    } else {
        base = (size_t)p * C * 960;
        n8 = C * 120;
    }
    const u16* x = sc + base;
    double s = 0.0, q = 0.0;
    for (int i = g * 256 + t; i < n8; i += G * 256) {
        u16x4 a = *(const u16x4*)&x[i * 8];
        u16x4 b = *(const u16x4*)&x[i * 8 + 4];
#pragma unroll
        for (int j = 0; j < 4; j++) {
            float fa = bf2f(a[j]), fb = bf2f(b[j]);
            s += (double)fa + (double)fb;
            q += (double)fa * fa + (double)fb * fb;
        }
    }
#pragma unroll
    for (int o = 32; o; o >>= 1) {
        s += __shfl_down(s, o);
        q += __shfl_down(q, o);
    }
    __shared__ double rs[4], rq[4];
    int w = t >> 6;
    if ((t & 63) == 0) {
        rs[w] = s;
        rq[w] = q;
    }
    __syncthreads();
    if (t == 0) {
        part[2 * ((size_t)p * G + g)] = rs[0] + rs[1] + rs[2] + rs[3];
        part[2 * ((size_t)p * G + g) + 1] = rq[0] + rq[1] + rq[2] + rq[3];
    }
}

// ---------------- stage 2 (fallback path only) ----------------
__global__ __launch_bounds__(64) void in_stats2(const double* __restrict__ part,
                                                float* __restrict__ stats,
                                                int G, int mode, int C) {
    int p = blockIdx.x, t = threadIdx.x;
    int cnt = (mode ? d_cs[p & 3] : C) * 960;
    double s = 0.0, q = 0.0;
    if (t < G) {
        s = part[2 * ((size_t)p * G + t)];
        q = part[2 * ((size_t)p * G + t) + 1];
    }
#pragma unroll
    for (int o = 32; o; o >>= 1) {
        s += __shfl_down(s, o);
        q += __shfl_down(q, o);
    }
    if (t == 0) {
        float mu = (float)(s / cnt);
        float var = (float)(q / cnt) - mu * mu;
        stats[2 * p] = mu;
        stats[2 * p + 1] = rsqrtf(var + 1e-5f);
    }
}

// ---------------- normalize + softmax -> prCat, stats2 FUSED (batched path, G=16) ----------------
__global__ __launch_bounds__(256) void norm_softmax_cat2(const u16* __restrict__ sc,
                                                         const double* __restrict__ part,
                                                         u16* __restrict__ prB) {
    int row = blockIdx.x;  // [0, 32*960): z*960 + c
    int z = row / 960, c = row - z * 960;
    int i = c < 512 ? 0 : (c < 768 ? 1 : (c < 896 ? 2 : 3));
    int plane = z * 4 + i;
    int b = z >> 2, h = z & 3;
    double s2 = 0.0, q2 = 0.0;
    for (int j = 0; j < 16; j++) {
        s2 += part[2 * ((size_t)plane * 16 + j)];
        q2 += part[2 * ((size_t)plane * 16 + j) + 1];
    }
    int cnt = d_cs[i] * 960;
    float mu = (float)(s2 / cnt);
    float var = (float)(q2 / cnt) - mu * mu;
    float rs = rsqrtf(var + 1e-5f);

    const u16* x = sc + (size_t)row * 960;
    u16* o = prB + (((size_t)b * 960 + c) * 4 + h) * 960;
    int t = threadIdx.x;
    bool act = t < 240;
    float v[4];
    float mx = -1e30f;
    if (act) {
        u16x4 d = *(const u16x4*)&x[t * 4];
#pragma unroll
        for (int j = 0; j < 4; j++) {
            v[j] = (bf2f(d[j]) - mu) * rs;
            mx = fmaxf(mx, v[j]);
        }
    }
    __shared__ float r1[4], r2[4];
#pragma unroll
    for (int o_ = 32; o_; o_ >>= 1) mx = fmaxf(mx, __shfl_xor(mx, o_));
    int w = t >> 6;
    if ((t & 63) == 0) r1[w] = mx;
    __syncthreads();
    mx = fmaxf(fmaxf(r1[0], r1[1]), fmaxf(r1[2], r1[3]));
    float s = 0.f;
    if (act) {
#pragma unroll
        for (int j = 0; j < 4; j++) {
            v[j] = __expf(v[j] - mx);
            s += v[j];
        }
    }
#pragma unroll
    for (int o_ = 32; o_; o_ >>= 1) s += __shfl_xor(s, o_);
    if ((t & 63) == 0) r2[w] = s;
    __syncthreads();
    s = r2[0] + r2[1] + r2[2] + r2[3];
    float inv = 1.0f / s;
    if (act) {
        u16x4 ov;
#pragma unroll
        for (int j = 0; j < 4; j++) ov[j] = f2bf(v[j] * inv);
        *(u16x4*)&o[t * 4] = ov;
    }
}

// ---------------- normalize + softmax, in-place (fallback path) ----------------
__global__ __launch_bounds__(256) void norm_softmax_ip(u16* sc,
                                                       const float* __restrict__ stats,
                                                       int C) {
    int row = blockIdx.x;
    int plane = row / C;
    u16* x = sc + (size_t)row * 960;
    float mu = stats[2 * plane], rs = stats[2 * plane + 1];
    int t = threadIdx.x;
    bool act = t < 240;
    float v[4];
    float mx = -1e30f;
    if (act) {
        u16x4 d = *(const u16x4*)&x[t * 4];
#pragma unroll
        for (int j = 0; j < 4; j++) {
            v[j] = (bf2f(d[j]) - mu) * rs;
            mx = fmaxf(mx, v[j]);
        }
    }
    __shared__ float r1[4], r2[4];
#pragma unroll
    for (int o = 32; o; o >>= 1) mx = fmaxf(mx, __shfl_xor(mx, o));
    int w = t >> 6;
    if ((t & 63) == 0) r1[w] = mx;
    __syncthreads();
    mx = fmaxf(fmaxf(r1[0], r1[1]), fmaxf(r1[2], r1[3]));
    float s = 0.f;
    if (act) {
#pragma unroll
        for (int j = 0; j < 4; j++) {
            v[j] = __expf(v[j] - mx);
            s += v[j];
        }
    }
#pragma unroll
    for (int o = 32; o; o >>= 1) s += __shfl_xor(s, o);
    if ((t & 63) == 0) r2[w] = s;
    __syncthreads();
    s = r2[0] + r2[1] + r2[2] + r2[3];
    float inv = 1.0f / s;
    if (act) {
        u16x4 o;
#pragma unroll
        for (int j = 0; j < 4; j++) o[j] = f2bf(v[j] * inv);
        *(u16x4*)&x[t * 4] = o;
    }
}

// ---------------- head-mean + transpose (fallback path only) ----------------
__global__ __launch_bounds__(256) void mean_heads(const u16* __restrict__ ctx, long ps,
                                                  u16* __restrict__ cm, int C) {
    int b = blockIdx.z;
    int n0 = blockIdx.x * 64, c0 = blockIdx.y * 64;
    __shared__ float sm[64][65];
    int t = threadIdx.x;
    float acc[16];
#pragma unroll
    for (int j = 0; j < 16; j++) acc[j] = 0.f;
    for (int h = 0; h < 4; h++) {
        const u16* p = ctx + (size_t)(b * 4 + h) * ps;
#pragma unroll
        for (int j = 0; j < 16; j++) {
            int lin = j * 256 + t;
            int cc = lin >> 6, nn = lin & 63;
            acc[j] += bf2f(p[(size_t)(c0 + cc) * 1024 + n0 + nn]);
        }
    }
#pragma unroll
    for (int j = 0; j < 16; j++) {
        int lin = j * 256 + t;
        sm[lin >> 6][lin & 63] = acc[j] * 0.25f;
    }
    __syncthreads();
#pragma unroll
    for (int j = 0; j < 16; j++) {
        int lin = j * 256 + t;
        int nn = lin >> 6, cc = lin & 63;
        cm[((size_t)b * 1024 + n0 + nn) * C + c0 + cc] = f2bf(sm[cc][nn]);
    }
}

extern "C" void kernel_launch(void* const* d_in, const int* in_sizes, int n_in,
                              void* d_out, int out_size, void* d_ws, size_t ws_size,
                              hipStream_t stream) {
    const int B = 8, NN = 1024, KV = 960;
    const int Cs[4] = {64, 128, 256, 512};
    const int offsIn[4] = {896, 768, 512, 0};  // row offset for input branch i
    const float* emb[4];
    for (int i = 0; i < 4; i++) emb[i] = (const float*)d_in[i];
    const float* embAll = (const float*)d_in[4];
    const float* Wq[4];
    for (int i = 0; i < 4; i++) Wq[i] = (const float*)d_in[5 + i];
    const float* Wk = (const float*)d_in[9];
    const float* Wv = (const float*)d_in[10];
    const float* Wo[4];
    for (int i = 0; i < 4; i++) Wo[i] = (const float*)d_in[11 + i];
    float* out = (float*)d_out;
    size_t outOff[4];
    {
        size_t o = 0;
        for (int i = 0; i < 4; i++) { outOff[i] = o; o += (size_t)B * NN * Cs[i]; }
    }

    const size_t SKV = 62914560;
    const size_t SSC = 58982400;
    const size_t SWQ = 2785280, SWO = 696320, SCM = 8388608;
    const size_t SPART = 131072, SST = 1024;
    const size_t SMALL = SWQ + SWO + SCM + SPART + SST;
    const size_t NEED_BAT = SSC + 3 * SKV + SMALL + 512;

    float invs = 1.0f / sqrtf((float)KV);
    auto g128 = [](int n) { return (n + 127) / 128; };

    if (ws_size >= NEED_BAT) {
        // ================= batched path =================
        char* p = (char*)d_ws;
        u16* scB = (u16*)p;        p += SSC;
        u16* QtB = (u16*)p;        p += SKV;
        u16* Kt = (u16*)p;         p += SKV;
        u16* VbC = (u16*)p;        p += SKV;
        u16* wq[4];
        for (int i = 0; i < 4; i++) { wq[i] = (u16*)p; p += (size_t)4 * Cs[i] * Cs[i] * 2; }
        u16* wo[4];
        for (int i = 0; i < 4; i++) { wo[i] = (u16*)p; p += (size_t)Cs[i] * Cs[i] * 2; }
        u16* cmX = (u16*)p;        p += SCM;
        double* part = (double*)p; p += SPART;
        (void)cmX;

        u16* eA = scB;
        u16* wk = (u16*)((char*)scB + 15728640);
        u16* wv = (u16*)((char*)scB + 23101440);
        u16* embB[4];
        {
            size_t eo = 30474240 / 2;
            for (int i = 0; i < 4; i++) {
                embB[i] = scB + eo;
                eo += (size_t)B * NN * Cs[i];
            }
        }
        u16* prB = QtB;
        u16* cmC = scB;

        // ---- single mega-cast: 15 segments ----
        {
            CastPack cp;
            int ns = 0;
            auto add = [&](const float* s, u16* d, size_t n) {
                cp.src[ns] = (const float4*)s;
                cp.dst[ns] = (u16x4*)d;
                cp.n4[ns] = (int)(n / 4);
                ns++;
            };
            add(embAll, eA, (size_t)B * NN * KV);
            add(Wk, wk, (size_t)4 * KV * KV);
            add(Wv, wv, (size_t)4 * KV * KV);
            for (int i = 0; i < 4; i++) add(Wq[i], wq[i], (size_t)4 * Cs[i] * Cs[i]);
            for (int i = 0; i < 4; i++) add(Wo[i], wo[i], (size_t)Cs[i] * Cs[i]);
            for (int i = 0; i < 4; i++) add(emb[i], embB[i], (size_t)B * NN * Cs[i]);
            cp.nseg = ns;
            cp.cum[0] = 0;
            for (int i = 0; i < ns; i++) {
                int nb = (cp.n4[i] + 1023) / 1024;
                if (nb < 1) nb = 1;
                cp.cum[i + 1] = cp.cum[i] + nb;
            }
            cast_multi<<<cp.cum[ns], 256, 0, stream>>>(cp);
        }

        // Kt[z][j][n]  (BK=32 -> 64 KiB LDS; allocator free -> 2 blocks/CU if VGPR<=128)
        gemm_nt_4ph<256, 32><<<dim3(4, 4, 32), 512, 0, stream>>>(
            wk, 0, (long)KV * KV, KV, eA, (long)NN * KV, 0, KV,
            Kt, 4 * 983040L, 983040L, NN, KV, NN, KV, 4, 1.0f);
        // VbCat[b][n][h*960+j]
        gemm_nt_4ph<256, 32><<<dim3(4, 4, 32), 512, 0, stream>>>(
            eA, (long)NN * KV, 0, KV, wv, 0, (long)KV * KV, KV,
            VbC, (long)NN * 3840, 960L, 3840, NN, KV, KV, 4, 1.0f);

        // Q-proj C=512
        gemm_nt_4ph<256, 32><<<dim3(4, 2, 32), 512, 0, stream>>>(
            wq[3], 0, 512L * 512, 512, embB[3], (long)NN * 512, 0, 512,
            QtB, 4 * 983040L, 983040L, NN, 512, NN, 512, 4, 1.0f);
        // Q-proj C in {64,128,256}: one grouped launch
        {
            GPack gp;
            gp.nseg = 3;
            gp.cum[0] = 0;
            for (int i = 0; i < 3; i++) {
                int C = Cs[i];
                GSeg& g = gp.s[i];
                g.A = wq[i]; g.sAb = 0; g.sAh = (long)C * C; g.lda = C;
                g.B = embB[i]; g.sBb = (long)NN * C; g.sBh = 0; g.ldb = C;
                g.Cp = (void*)(QtB + (size_t)offsIn[i] * 1024);
                g.sCb = 4 * 983040L; g.sCh = 983040L; g.ldc = NN;
                g.M = C; g.N = NN; g.K = C; g.hdiv = 4;
                g.gx = 8; g.gy = g128(C); g.isF32 = 0; g.alpha = 1.0f;
                gp.cum[i + 1] = gp.cum[i] + g.gx * g.gy * 32;
            }
            gemm_nt128_grp<<<gp.cum[3], 256, 0, stream>>>(gp);
        }
        // one big QK: scB[z][960 c][960 k] bf16
        gemm_nt_4ph<256, 32><<<dim3(4, 4, 32), 512, 0, stream>>>(
            QtB, 983040L, 0, NN, Kt, 983040L, 0, NN,
            scB, 921600L, 0, KV, 960, KV, NN, 1, invs);
        // instance-norm stats (128 planes) + softmax (stats2 fused) -> prCat
        in_stats1<<<dim3(16, 128), 256, 0, stream>>>(scB, part, 16, 1, 0);
        norm_softmax_cat2<<<32 * 960, 256, 0, stream>>>(scB, part, prB);
        // fused PV + head-mean (BM=128, BK=64; grid 256 = 1/CU, grid-limited)
        gemm_nt_4ph<128, 64><<<dim3(4, 8, 8), 512, 0, stream>>>(
            VbC, (long)NN * 3840, 0, 3840, prB, (long)960 * 3840, 0, 3840,
            cmC, (long)NN * 960, 0, 960, NN, 960, 3840, 1, 0.25f);
        // out-proj: all 4 branches in one grouped launch (f32 epilogue)
        {
            GPack gp;
            gp.nseg = 4;
            gp.cum[0] = 0;
            for (int i = 0; i < 4; i++) {
                int C = Cs[i];
                GSeg& g = gp.s[i];
                g.A = cmC + offsIn[i]; g.sAb = (long)NN * 960; g.sAh = 0; g.lda = 960;
                g.B = wo[i]; g.sBb = 0; g.sBh = 0; g.ldb = C;
                g.Cp = (void*)(out + outOff[i]);
                g.sCb = (long)NN * C; g.sCh = 0; g.ldc = C;
                g.M = NN; g.N = C; g.K = C; g.hdiv = 1;
                g.gx = g128(C); g.gy = 8; g.isF32 = 1; g.alpha = 1.0f;
                gp.cum[i + 1] = gp.cum[i] + g.gx * g.gy * 8;
            }
            gemm_nt128_grp<<<gp.cum[4], 256, 0, stream>>>(gp);
        }
    } else {
        // ================= fallback per-branch path (~205 MB) =================
        const size_t S1 = 33554432, S2 = 33554432;
        if (ws_size < S1 + S2 + 2 * SKV + SMALL + 512) return;
        char* p = (char*)d_ws;
        char* buf1 = p;            p += S1;
        char* buf2 = p;            p += S2;
        u16* Kt = (u16*)p;         p += SKV;
        u16* Vb = (u16*)p;         p += SKV;
        u16* wq[4];
        for (int i = 0; i < 4; i++) { wq[i] = (u16*)p; p += (size_t)4 * Cs[i] * Cs[i] * 2; }
        u16* wo[4];
        for (int i = 0; i < 4; i++) { wo[i] = (u16*)p; p += (size_t)Cs[i] * Cs[i] * 2; }
        u16* cmX = (u16*)p;        p += SCM;
        double* part = (double*)p; p += SPART;
        float* stats = (float*)p;

        u16* eA = (u16*)buf1;
        u16* wk = (u16*)(buf1 + 15728640);
        u16* wv = (u16*)(buf1 + 23101440);
        u16* sc = (u16*)buf1;
        u16* Qt = (u16*)buf2;
        u16* ctx = (u16*)buf2;

        auto castL = [&](const float* s, u16* d, size_t n) {
            int n4 = (int)(n / 4);
            cast_bf16<<<(n4 + 255) / 256, 256, 0, stream>>>((const float4*)s, (u16x4*)d, n4);
        };
        castL(embAll, eA, (size_t)B * NN * KV);
        castL(Wk, wk, (size_t)4 * KV * KV);
        castL(Wv, wv, (size_t)4 * KV * KV);
        for (int i = 0; i < 4; i++) castL(Wq[i], wq[i], (size_t)4 * Cs[i] * Cs[i]);
        for (int i = 0; i < 4; i++) castL(Wo[i], wo[i], (size_t)Cs[i] * Cs[i]);

        gemm_nt128<u16><<<dim3(8, 8, 32), 256, 0, stream>>>(
            wk, 0, (long)KV * KV, KV, eA, (long)NN * KV, 0, KV,
            Kt, 4 * 983040L, 983040L, NN, KV, NN, KV, 4, 1.0f);
        gemm_nt128<u16><<<dim3(8, 8, 32), 256, 0, stream>>>(
            eA, (long)NN * KV, 0, KV, wv, 0, (long)KV * KV, KV,
            Vb, 4 * 983040L, 983040L, KV, NN, KV, KV, 4, 1.0f);

        for (int i = 0; i < 4; i++) {
            int C = Cs[i];
            castL(emb[i], cmX, (size_t)B * NN * C);
            gemm_nt128<u16><<<dim3(8, g128(C), 32), 256, 0, stream>>>(
                wq[i], 0, (long)C * C, C, cmX, (long)NN * C, 0, C,
                Qt, 4L * C * NN, (long)C * NN, NN, C, NN, C, 4, 1.0f);
            gemm_nt128<u16><<<dim3(8, g128(C), 32), 256, 0, stream>>>(
                Qt, (long)C * NN, 0, NN, Kt, 983040L, 0, NN,
                sc, (long)C * KV, 0, KV, C, KV, NN, 1, invs);
            in_stats1<<<dim3(64, 32), 256, 0, stream>>>(sc, part, 64, 0, C);
            in_stats2<<<32, 64, 0, stream>>>(part, stats, 64, 0, C);
            norm_softmax_ip<<<32 * C, 256, 0, stream>>>(sc, stats, C);
            gemm_nt128<u16><<<dim3(8, g128(C), 32), 256, 0, stream>>>(
                sc, (long)C * KV, 0, KV, Vb, 983040L, 0, KV,
                ctx, (long)C * NN, 0, NN, C, NN, KV, 1, 1.0f);
            mean_heads<<<dim3(16, C / 64, B), 256, 0, stream>>>(
                ctx, (long)C * NN, cmX, C);
            gemm_nt128<float><<<dim3(g128(C), 8, B), 256, 0, stream>>>(
                cmX, (long)NN * C, 0, C, wo[i], 0, 0, C,
                out + outOff[i], (long)NN * C, 0, C, NN, C, C, 1, 1.0f);
        }
    }
}

// Round 17
// 400.041 us; speedup vs baseline: 1.0313x; 1.0313x over previous
//
#include <hip/hip_runtime.h>
#include <stdint.h>

typedef unsigned short u16;
typedef short bf16x8 __attribute__((ext_vector_type(8)));
typedef float f32x4 __attribute__((ext_vector_type(4)));
typedef u16 u16x4 __attribute__((ext_vector_type(4)));

__device__ __forceinline__ u16 f2bf(float f) {
    unsigned u = __builtin_bit_cast(unsigned, f);
    unsigned r = (u + 0x7fffu + ((u >> 16) & 1u)) >> 16;
    return (u16)r;
}
__device__ __forceinline__ float bf2f(u16 h) {
    unsigned u = ((unsigned)h) << 16;
    return __builtin_bit_cast(float, u);
}

typedef const __attribute__((address_space(1))) unsigned int* gptr_t;
typedef __attribute__((address_space(3))) unsigned int* lptr_t;
__device__ __forceinline__ void gload16(const void* g, void* l) {
    __builtin_amdgcn_global_load_lds((gptr_t)(uintptr_t)g, (lptr_t)(uintptr_t)l, 16, 0, 0);
}

// branch tables: rows of the concatenated 960-row score/Q space
__device__ __constant__ int d_offs[4] = {0, 512, 768, 896};
__device__ __constant__ int d_cs[4] = {512, 256, 128, 64};

// ---------------- single cast (fallback path) ----------------
__global__ __launch_bounds__(256) void cast_bf16(const float4* __restrict__ in,
                                                 u16x4* __restrict__ out, int n4) {
    int i = blockIdx.x * 256 + threadIdx.x;
    if (i < n4) {
        float4 f = in[i];
        u16x4 o = {f2bf(f.x), f2bf(f.y), f2bf(f.z), f2bf(f.w)};
        out[i] = o;
    }
}

// ---------------- multi-segment cast: one launch for all f32->bf16 ----------------
struct CastPack {
    const float4* src[15];
    u16x4* dst[15];
    int n4[15];
    int cum[16];
    int nseg;
};
__global__ __launch_bounds__(256) void cast_multi(CastPack p) {
    int b = blockIdx.x, t = threadIdx.x;
    int s = 0;
    while (s + 1 < p.nseg && b >= p.cum[s + 1]) s++;
    int lb = b - p.cum[s], nb = p.cum[s + 1] - p.cum[s];
    const float4* src = p.src[s];
    u16x4* dst = p.dst[s];
    int n4 = p.n4[s];
    for (int i = lb * 256 + t; i < n4; i += nb * 256) {
        float4 f = src[i];
        u16x4 o = {f2bf(f.x), f2bf(f.y), f2bf(f.z), f2bf(f.w)};
        dst[i] = o;
    }
}

// ======== 2-phase-per-K-tile NT GEMM (32-MFMA clusters, minimal barriers; r11/r12 engine) ========
// Best measured variant (400.4 us total; QK ~73 us, MfmaUtil 38%, 0 bank conflicts).
// Per tile k:
//  p0: BRD + ARD-lo (issue); stA(k+1)->nbuf; lgkm(0); MFMA-lo
//  p1: ARD-hi (issue); BARRIER (B slots dead); stB(k+2)->buf[k]; lgkm(0); MFMA-hi;
//      counted vmcnt(4); BARRIER (publish buf[k+1])
#define ARDH(DST, BUFO, H)                                                         \
    _Pragma("unroll") for (int f = 0; f < HMF; f++)                                \
        _Pragma("unroll") for (int kb = 0; kb < 2; kb++) {                         \
            int rl = ((H)*HMF + f) * 16 + la;                                      \
            DST[f][kb] = *(const bf16x8*)&lds[(BUFO) + rl * 64 +                   \
                                              (((kb * 4 + lk4) ^ (rl & 7)) << 3)]; \
        }
#define BRD(BUFO)                                                                  \
    _Pragma("unroll") for (int ni = 0; ni < 4; ni++)                               \
        _Pragma("unroll") for (int kb = 0; kb < 2; kb++) {                         \
            int rl = brow0 + ni * 16 + la;                                         \
            breg[ni][kb] = *(const bf16x8*)&lds[(BUFO) + rl * 64 +                 \
                                                (((kb * 4 + lk4) ^ (rl & 7)) << 3)]; \
        }
#define MMAH(H, SRC)                                                               \
    __builtin_amdgcn_sched_barrier(0);                                             \
    __builtin_amdgcn_s_setprio(1);                                                 \
    _Pragma("unroll") for (int f = 0; f < HMF; f++)                                \
        _Pragma("unroll") for (int ni = 0; ni < 4; ni++)                           \
            _Pragma("unroll") for (int kb = 0; kb < 2; kb++)                       \
                acc[(H)*HMF + f][ni] = __builtin_amdgcn_mfma_f32_16x16x32_bf16(    \
                    SRC[f][kb], breg[ni][kb], acc[(H)*HMF + f][ni], 0, 0, 0);      \
    __builtin_amdgcn_s_setprio(0);
#define WLG0 asm volatile("s_waitcnt lgkmcnt(0)" ::: "memory")

template <int BM>
__global__ __launch_bounds__(512, 2) void gemm_nt_4ph(
    const u16* __restrict__ A, long sAb, long sAh, int lda,
    const u16* __restrict__ B, long sBb, long sBh, int ldb,
    u16* __restrict__ C, long sCb, long sCh, int ldc,
    int M, int N, int K, int hdiv, float alpha) {
    constexpr int NA = BM / 128;
    constexpr int WTM = BM / 2;
    constexpr int NMF = WTM / 16;
    constexpr int HMF = NMF / 2;
    constexpr int APART = WTM * 64;
    constexpr int BPART = 128 * 64;
    constexpr int BUFSZ = 2 * APART + 2 * BPART;
    __shared__ u16 lds[2 * BUFSZ];

    // bijective XCD swizzle (m204)
    int gx = gridDim.x, gy = gridDim.y;
    int nwg = gx * gy * gridDim.z;
    int orig = blockIdx.x + gx * (blockIdx.y + gy * blockIdx.z);
    int q = nwg >> 3, r = nwg & 7;
    int xcd = orig & 7, seq = orig >> 3;
    int wg = (xcd < r ? xcd * (q + 1) : r * (q + 1) + (xcd - r) * q) + seq;
    int bx = wg % gx, tmpw = wg / gx;
    int by = tmpw % gy, bz = tmpw / gy;

    int bb = bz / hdiv, hh = bz - bb * hdiv;
    const u16* Ab = A + (size_t)bb * sAb + (size_t)hh * sAh;
    const u16* Bb = B + (size_t)bb * sBb + (size_t)hh * sBh;
    u16* Cb = C + (size_t)bb * sCb + (size_t)hh * sCh;
    int tm = by * BM, tn = bx * 256;
    int t = threadIdx.x, lane = t & 63, w = t >> 6;
    int wm = w >> 2, wn = w & 3;
    int la = lane & 15, lk4 = lane >> 4;
    int brow0 = (wn & 1) * 64;

    const u16* pA0[NA];
    const u16* pA1[NA];
    const u16* pB0[2];
    const u16* pB1[2];
#pragma unroll
    for (int i = 0; i < NA; i++) {
        int seg = i * 512 + t;
        int col = (((seg & 7) ^ ((seg >> 3) & 7)) << 3);
        int r0 = tm + (seg >> 3);
        if (r0 > M - 1) r0 = M - 1;
        pA0[i] = Ab + (size_t)r0 * lda + col;
        int r1 = tm + WTM + (seg >> 3);
        if (r1 > M - 1) r1 = M - 1;
        pA1[i] = Ab + (size_t)r1 * lda + col;
    }
#pragma unroll
    for (int i = 0; i < 2; i++) {
        int seg = i * 512 + t;
        int col = (((seg & 7) ^ ((seg >> 3) & 7)) << 3);
        int r0 = tn + (seg >> 3);
        if (r0 > N - 1) r0 = N - 1;
        pB0[i] = Bb + (size_t)r0 * ldb + col;
        int r1 = tn + 128 + (seg >> 3);
        if (r1 > N - 1) r1 = N - 1;
        pB1[i] = Bb + (size_t)r1 * ldb + col;
    }

    auto AOF = [&](int buf, int h) { return buf * BUFSZ + h * APART; };
    auto BOF = [&](int buf, int h) { return buf * BUFSZ + 2 * APART + h * BPART; };
    auto stA0 = [&](int buf) {
#pragma unroll
        for (int i = 0; i < NA; i++) {
            gload16(pA0[i], &lds[AOF(buf, 0) + (i * 512 + t) * 8]);
            pA0[i] += 64;
        }
    };
    auto stA1 = [&](int buf) {
#pragma unroll
        for (int i = 0; i < NA; i++) {
            gload16(pA1[i], &lds[AOF(buf, 1) + (i * 512 + t) * 8]);
            pA1[i] += 64;
        }
    };
    auto stB0 = [&](int buf) {
#pragma unroll
        for (int i = 0; i < 2; i++) {
            gload16(pB0[i], &lds[BOF(buf, 0) + (i * 512 + t) * 8]);
            pB0[i] += 64;
        }
    };
    auto stB1 = [&](int buf) {
#pragma unroll
        for (int i = 0; i < 2; i++) {
            gload16(pB1[i], &lds[BOF(buf, 1) + (i * 512 + t) * 8]);
            pB1[i] += 64;
        }
    };

    int nt = K / 64;
    stA0(0);
    stA1(0);
    stB0(0);
    stB1(0);
    if (nt > 1) {
        stB0(1);
        stB1(1);
        asm volatile("s_waitcnt vmcnt(4)" ::: "memory");
    } else {
        asm volatile("s_waitcnt vmcnt(0)" ::: "memory");
    }
    __builtin_amdgcn_s_barrier();

    f32x4 acc[NMF][4] = {};
    bf16x8 breg[4][2];
    bf16x8 aLo[HMF][2], aHi[HMF][2];

    for (int k = 0; k < nt; ++k) {
        int buf = k & 1, nbuf = buf ^ 1;
        int ao = AOF(buf, wm), bo = BOF(buf, wn >> 1);
        bool s1 = (k + 1 < nt), s2 = (k + 2 < nt);
        // p0: B + A-lo reads; stage A(k+1); 32-MFMA cluster (no barrier needed)
        BRD(bo)
        ARDH(aLo, ao, 0)
        if (s1) {
            stA0(nbuf);
            stA1(nbuf);
        }
        WLG0;
        MMAH(0, aLo)
        // p1: A-hi reads; barrier; stage B(k+2) into dead slots; 32-MFMA; publish
        ARDH(aHi, ao, 1)
        __builtin_amdgcn_s_barrier();  // all waves' p0 lgkm(0) done -> B slots dead
        if (s2) {
            stB0(buf);
            stB1(buf);
        }
        WLG0;
        MMAH(1, aHi)
        if (s2)
            asm volatile("s_waitcnt vmcnt(4)" ::: "memory");
        else
            asm volatile("s_waitcnt vmcnt(0)" ::: "memory");
        __builtin_amdgcn_s_barrier();  // publish buf[k+1] DMA
    }
#pragma unroll
    for (int mi = 0; mi < NMF; mi++)
#pragma unroll
        for (int ni = 0; ni < 4; ni++)
#pragma unroll
            for (int r_ = 0; r_ < 4; r_++) {
                int m = tm + wm * WTM + mi * 16 + ((lane >> 4) << 2) + r_;
                int n = tn + wn * 64 + ni * 16 + la;
                if (m < M && n < N)
                    Cb[(size_t)m * ldc + n] = f2bf(acc[mi][ni][r_] * alpha);
            }
}

// ---------------- NT GEMM (m97 1-phase, 128 tile), plain (fallback) ----------------
template <typename OUT>
__global__ __launch_bounds__(256) void gemm_nt128(
    const u16* __restrict__ A, long sAb, long sAh, int lda,
    const u16* __restrict__ B, long sBb, long sBh, int ldb,
    OUT* __restrict__ C, long sCb, long sCh, int ldc,
    int M, int N, int K, int hdiv, float alpha) {
    __shared__ u16 sA[128 * 64];
    __shared__ u16 sB[128 * 64];
    int gx = gridDim.x, gy = gridDim.y;
    int nwg = gx * gy * gridDim.z;
    int orig = blockIdx.x + gx * (blockIdx.y + gy * blockIdx.z);
    int q = nwg >> 3, r = nwg & 7;
    int xcd = orig & 7, seq = orig >> 3;
    int wg = (xcd < r ? xcd * (q + 1) : r * (q + 1) + (xcd - r) * q) + seq;
    int bx = wg % gx, tmpw = wg / gx;
    int by = tmpw % gy, bz = tmpw / gy;

    int bb = bz / hdiv, hh = bz - bb * hdiv;
    const u16* Ab = A + (size_t)bb * sAb + (size_t)hh * sAh;
    const u16* Bb = B + (size_t)bb * sBb + (size_t)hh * sBh;
    OUT* Cb = C + (size_t)bb * sCb + (size_t)hh * sCh;
    int tm = by * 128, tn = bx * 128;
    int t = threadIdx.x, lane = t & 63, w = t >> 6;
    int wr = w >> 1, wc = w & 1;
    int r0 = t >> 3, c0 = (t & 7) * 8;
    const u16* gA[4];
    const u16* gB[4];
#pragma unroll
    for (int i = 0; i < 4; i++) {
        int ar = tm + i * 32 + r0;
        if (ar > M - 1) ar = M - 1;
        gA[i] = Ab + (size_t)ar * lda + c0;
    }
#pragma unroll
    for (int i = 0; i < 4; i++) {
        int br = tn + i * 32 + r0;
        if (br > N - 1) br = N - 1;
        gB[i] = Bb + (size_t)br * ldb + c0;
    }
    f32x4 acc[4][4] = {};
    int la = lane & 15, lk = (lane >> 4) * 8;
    for (int k0 = 0; k0 < K; k0 += 64) {
#pragma unroll
        for (int i = 0; i < 4; i++) {
            gload16(gA[i], &sA[(i * 256 + t) * 8]);
            gA[i] += 64;
        }
#pragma unroll
        for (int i = 0; i < 4; i++) {
            gload16(gB[i], &sB[(i * 256 + t) * 8]);
            gB[i] += 64;
        }
        __syncthreads();
#pragma unroll
        for (int kk = 0; kk < 64; kk += 32) {
            bf16x8 a[4], b[4];
#pragma unroll
            for (int mi = 0; mi < 4; mi++)
                a[mi] = *(const bf16x8*)&sA[(wr * 64 + mi * 16 + la) * 64 + kk + lk];
#pragma unroll
            for (int ni = 0; ni < 4; ni++)
                b[ni] = *(const bf16x8*)&sB[(wc * 64 + ni * 16 + la) * 64 + kk + lk];
#pragma unroll
            for (int mi = 0; mi < 4; mi++)
#pragma unroll
                for (int ni = 0; ni < 4; ni++)
                    acc[mi][ni] = __builtin_amdgcn_mfma_f32_16x16x32_bf16(
                        a[mi], b[ni], acc[mi][ni], 0, 0, 0);
        }
        __syncthreads();
    }
#pragma unroll
    for (int mi = 0; mi < 4; mi++)
#pragma unroll
        for (int ni = 0; ni < 4; ni++)
#pragma unroll
            for (int r_ = 0; r_ < 4; r_++) {
                int m = tm + wr * 64 + mi * 16 + (lane >> 4) * 4 + r_;
                int n = tn + wc * 64 + ni * 16 + la;
                if (m < M && n < N) {
                    float v = acc[mi][ni][r_] * alpha;
                    if constexpr (sizeof(OUT) == 4)
                        Cb[(size_t)m * ldc + n] = v;
                    else
                        Cb[(size_t)m * ldc + n] = f2bf(v);
                }
            }
}

// ---------------- grouped 128-tile NT GEMM: several segments in one launch ----------------
struct GSeg {
    const u16* A; long sAb, sAh; int lda;
    const u16* B; long sBb, sBh; int ldb;
    void* Cp; long sCb, sCh; int ldc;
    int M, N, K, hdiv, gx, gy, isF32;
    float alpha;
};
struct GPack {
    GSeg s[4];
    int cum[5];
    int nseg;
};
__global__ __launch_bounds__(256) void gemm_nt128_grp(GPack p) {
    int nwg = p.cum[p.nseg];
    int orig = blockIdx.x;
    int q = nwg >> 3, r = nwg & 7;
    int xcd = orig & 7, seq = orig >> 3;
    int wg = (xcd < r ? xcd * (q + 1) : r * (q + 1) + (xcd - r) * q) + seq;
    int s = 0;
    while (s + 1 < p.nseg && wg >= p.cum[s + 1]) s++;
    GSeg g;
    if (s == 0) g = p.s[0];
    else if (s == 1) g = p.s[1];
    else if (s == 2) g = p.s[2];
    else g = p.s[3];
    int lm = wg - p.cum[s];
    int bx = lm % g.gx;
    int rest = lm / g.gx;
    int by = rest % g.gy, bz = rest / g.gy;

    __shared__ u16 sA[128 * 64];
    __shared__ u16 sB[128 * 64];
    int bb = bz / g.hdiv, hh = bz - bb * g.hdiv;
    const u16* Ab = g.A + (size_t)bb * g.sAb + (size_t)hh * g.sAh;
    const u16* Bb = g.B + (size_t)bb * g.sBb + (size_t)hh * g.sBh;
    int tm = by * 128, tn = bx * 128;
    int t = threadIdx.x, lane = t & 63, w = t >> 6;
    int wr = w >> 1, wc = w & 1;
    int r0 = t >> 3, c0 = (t & 7) * 8;
    const u16* gA[4];
    const u16* gB[4];
#pragma unroll
    for (int i = 0; i < 4; i++) {
        int ar = tm + i * 32 + r0;
        if (ar > g.M - 1) ar = g.M - 1;
        gA[i] = Ab + (size_t)ar * g.lda + c0;
    }
#pragma unroll
    for (int i = 0; i < 4; i++) {
        int br = tn + i * 32 + r0;
        if (br > g.N - 1) br = g.N - 1;
        gB[i] = Bb + (size_t)br * g.ldb + c0;
    }
    f32x4 acc[4][4] = {};
    int la = lane & 15, lk = (lane >> 4) * 8;
    for (int k0 = 0; k0 < g.K; k0 += 64) {
#pragma unroll
        for (int i = 0; i < 4; i++) {
            gload16(gA[i], &sA[(i * 256 + t) * 8]);
            gA[i] += 64;
        }
#pragma unroll
        for (int i = 0; i < 4; i++) {
            gload16(gB[i], &sB[(i * 256 + t) * 8]);
            gB[i] += 64;
        }
        __syncthreads();
#pragma unroll
        for (int kk = 0; kk < 64; kk += 32) {
            bf16x8 a[4], b[4];
#pragma unroll
            for (int mi = 0; mi < 4; mi++)
                a[mi] = *(const bf16x8*)&sA[(wr * 64 + mi * 16 + la) * 64 + kk + lk];
#pragma unroll
            for (int ni = 0; ni < 4; ni++)
                b[ni] = *(const bf16x8*)&sB[(wc * 64 + ni * 16 + la) * 64 + kk + lk];
#pragma unroll
            for (int mi = 0; mi < 4; mi++)
#pragma unroll
                for (int ni = 0; ni < 4; ni++)
                    acc[mi][ni] = __builtin_amdgcn_mfma_f32_16x16x32_bf16(
                        a[mi], b[ni], acc[mi][ni], 0, 0, 0);
        }
        __syncthreads();
    }
    if (g.isF32) {
        float* Cb = (float*)g.Cp + (size_t)bb * g.sCb + (size_t)hh * g.sCh;
#pragma unroll
        for (int mi = 0; mi < 4; mi++)
#pragma unroll
            for (int ni = 0; ni < 4; ni++)
#pragma unroll
                for (int r_ = 0; r_ < 4; r_++) {
                    int m = tm + wr * 64 + mi * 16 + (lane >> 4) * 4 + r_;
                    int n = tn + wc * 64 + ni * 16 + la;
                    if (m < g.M && n < g.N)
                        Cb[(size_t)m * g.ldc + n] = acc[mi][ni][r_] * g.alpha;
                }
    } else {
        u16* Cb = (u16*)g.Cp + (size_t)bb * g.sCb + (size_t)hh * g.sCh;
#pragma unroll
        for (int mi = 0; mi < 4; mi++)
#pragma unroll
            for (int ni = 0; ni < 4; ni++)
#pragma unroll
                for (int r_ = 0; r_ < 4; r_++) {
                    int m = tm + wr * 64 + mi * 16 + (lane >> 4) * 4 + r_;
                    int n = tn + wc * 64 + ni * 16 + la;
                    if (m < g.M && n < g.N)
                        Cb[(size_t)m * g.ldc + n] = f2bf(acc[mi][ni][r_] * g.alpha);
                }
    }
}

// ---------------- instance-norm stats, stage 1 (bf16 input, two-stage deterministic) ----------------
__global__ __launch_bounds__(256) void in_stats1(const u16* __restrict__ sc,
                                                 double* __restrict__ part,
                                                 int G, int mode, int C) {
    int p = blockIdx.y, g = blockIdx.x, t = threadIdx.x;
    size_t base;
    int n8;
    if (mode) {
        int z = p >> 2, i = p & 3;
        base = (size_t)z * 921600 + (size_t)d_offs[i] * 960;
        n8 = d_cs[i] * 120;
    } else {
        base = (size_t)p * C * 960;
        n8 = C * 120;
    }
    const u16* x = sc + base;
    double s = 0.0, q = 0.0;
    for (int i = g * 256 + t; i < n8; i += G * 256) {
        u16x4 a = *(const u16x4*)&x[i * 8];
        u16x4 b = *(const u16x4*)&x[i * 8 + 4];
#pragma unroll
        for (int j = 0; j < 4; j++) {
            float fa = bf2f(a[j]), fb = bf2f(b[j]);
            s += (double)fa + (double)fb;
            q += (double)fa * fa + (double)fb * fb;
        }
    }
#pragma unroll
    for (int o = 32; o; o >>= 1) {
        s += __shfl_down(s, o);
        q += __shfl_down(q, o);
    }
    __shared__ double rs[4], rq[4];
    int w = t >> 6;
    if ((t & 63) == 0) {
        rs[w] = s;
        rq[w] = q;
    }
    __syncthreads();
    if (t == 0) {
        part[2 * ((size_t)p * G + g)] = rs[0] + rs[1] + rs[2] + rs[3];
        part[2 * ((size_t)p * G + g) + 1] = rq[0] + rq[1] + rq[2] + rq[3];
    }
}

// ---------------- stage 2 (fallback path only) ----------------
__global__ __launch_bounds__(64) void in_stats2(const double* __restrict__ part,
                                                float* __restrict__ stats,
                                                int G, int mode, int C) {
    int p = blockIdx.x, t = threadIdx.x;
    int cnt = (mode ? d_cs[p & 3] : C) * 960;
    double s = 0.0, q = 0.0;
    if (t < G) {
        s = part[2 * ((size_t)p * G + t)];
        q = part[2 * ((size_t)p * G + t) + 1];
    }
#pragma unroll
    for (int o = 32; o; o >>= 1) {
        s += __shfl_down(s, o);
        q += __shfl_down(q, o);
    }
    if (t == 0) {
        float mu = (float)(s / cnt);
        float var = (float)(q / cnt) - mu * mu;
        stats[2 * p] = mu;
        stats[2 * p + 1] = rsqrtf(var + 1e-5f);
    }
}

// ---------------- normalize + softmax -> prCat, stats2 FUSED (batched path, G=16) ----------------
__global__ __launch_bounds__(256) void norm_softmax_cat2(const u16* __restrict__ sc,
                                                         const double* __restrict__ part,
                                                         u16* __restrict__ prB) {
    int row = blockIdx.x;  // [0, 32*960): z*960 + c
    int z = row / 960, c = row - z * 960;
    int i = c < 512 ? 0 : (c < 768 ? 1 : (c < 896 ? 2 : 3));
    int plane = z * 4 + i;
    int b = z >> 2, h = z & 3;
    double s2 = 0.0, q2 = 0.0;
    for (int j = 0; j < 16; j++) {
        s2 += part[2 * ((size_t)plane * 16 + j)];
        q2 += part[2 * ((size_t)plane * 16 + j) + 1];
    }
    int cnt = d_cs[i] * 960;
    float mu = (float)(s2 / cnt);
    float var = (float)(q2 / cnt) - mu * mu;
    float rs = rsqrtf(var + 1e-5f);

    const u16* x = sc + (size_t)row * 960;
    u16* o = prB + (((size_t)b * 960 + c) * 4 + h) * 960;
    int t = threadIdx.x;
    bool act = t < 240;
    float v[4];
    float mx = -1e30f;
    if (act) {
        u16x4 d = *(const u16x4*)&x[t * 4];
#pragma unroll
        for (int j = 0; j < 4; j++) {
            v[j] = (bf2f(d[j]) - mu) * rs;
            mx = fmaxf(mx, v[j]);
        }
    }
    __shared__ float r1[4], r2[4];
#pragma unroll
    for (int o_ = 32; o_; o_ >>= 1) mx = fmaxf(mx, __shfl_xor(mx, o_));
    int w = t >> 6;
    if ((t & 63) == 0) r1[w] = mx;
    __syncthreads();
    mx = fmaxf(fmaxf(r1[0], r1[1]), fmaxf(r1[2], r1[3]));
    float s = 0.f;
    if (act) {
#pragma unroll
        for (int j = 0; j < 4; j++) {
            v[j] = __expf(v[j] - mx);
            s += v[j];
        }
    }
#pragma unroll
    for (int o_ = 32; o_; o_ >>= 1) s += __shfl_xor(s, o_);
    if ((t & 63) == 0) r2[w] = s;
    __syncthreads();
    s = r2[0] + r2[1] + r2[2] + r2[3];
    float inv = 1.0f / s;
    if (act) {
        u16x4 ov;
#pragma unroll
        for (int j = 0; j < 4; j++) ov[j] = f2bf(v[j] * inv);
        *(u16x4*)&o[t * 4] = ov;
    }
}

// ---------------- normalize + softmax, in-place (fallback path) ----------------
__global__ __launch_bounds__(256) void norm_softmax_ip(u16* sc,
                                                       const float* __restrict__ stats,
                                                       int C) {
    int row = blockIdx.x;
    int plane = row / C;
    u16* x = sc + (size_t)row * 960;
    float mu = stats[2 * plane], rs = stats[2 * plane + 1];
    int t = threadIdx.x;
    bool act = t < 240;
    float v[4];
    float mx = -1e30f;
    if (act) {
        u16x4 d = *(const u16x4*)&x[t * 4];
#pragma unroll
        for (int j = 0; j < 4; j++) {
            v[j] = (bf2f(d[j]) - mu) * rs;
            mx = fmaxf(mx, v[j]);
        }
    }
    __shared__ float r1[4], r2[4];
#pragma unroll
    for (int o = 32; o; o >>= 1) mx = fmaxf(mx, __shfl_xor(mx, o));
    int w = t >> 6;
    if ((t & 63) == 0) r1[w] = mx;
    __syncthreads();
    mx = fmaxf(fmaxf(r1[0], r1[1]), fmaxf(r1[2], r1[3]));
    float s = 0.f;
    if (act) {
#pragma unroll
        for (int j = 0; j < 4; j++) {
            v[j] = __expf(v[j] - mx);
            s += v[j];
        }
    }
#pragma unroll
    for (int o = 32; o; o >>= 1) s += __shfl_xor(s, o);
    if ((t & 63) == 0) r2[w] = s;
    __syncthreads();
    s = r2[0] + r2[1] + r2[2] + r2[3];
    float inv = 1.0f / s;
    if (act) {
        u16x4 o;
#pragma unroll
        for (int j = 0; j < 4; j++) o[j] = f2bf(v[j] * inv);
        *(u16x4*)&x[t * 4] = o;
    }
}

// ---------------- head-mean + transpose (fallback path only) ----------------
__global__ __launch_bounds__(256) void mean_heads(const u16* __restrict__ ctx, long ps,
                                                  u16* __restrict__ cm, int C) {
    int b = blockIdx.z;
    int n0 = blockIdx.x * 64, c0 = blockIdx.y * 64;
    __shared__ float sm[64][65];
    int t = threadIdx.x;
    float acc[16];
#pragma unroll
    for (int j = 0; j < 16; j++) acc[j] = 0.f;
    for (int h = 0; h < 4; h++) {
        const u16* p = ctx + (size_t)(b * 4 + h) * ps;
#pragma unroll
        for (int j = 0; j < 16; j++) {
            int lin = j * 256 + t;
            int cc = lin >> 6, nn = lin & 63;
            acc[j] += bf2f(p[(size_t)(c0 + cc) * 1024 + n0 + nn]);
        }
    }
#pragma unroll
    for (int j = 0; j < 16; j++) {
        int lin = j * 256 + t;
        sm[lin >> 6][lin & 63] = acc[j] * 0.25f;
    }
    __syncthreads();
#pragma unroll
    for (int j = 0; j < 16; j++) {
        int lin = j * 256 + t;
        int nn = lin >> 6, cc = lin & 63;
        cm[((size_t)b * 1024 + n0 + nn) * C + c0 + cc] = f2bf(sm[cc][nn]);
    }
}

extern "C" void kernel_launch(void* const* d_in, const int* in_sizes, int n_in,
                              void* d_out, int out_size, void* d_ws, size_t ws_size,
                              hipStream_t stream) {
    const int B = 8, NN = 1024, KV = 960;
    const int Cs[4] = {64, 128, 256, 512};
    const int offsIn[4] = {896, 768, 512, 0};  // row offset for input branch i
    const float* emb[4];
    for (int i = 0; i < 4; i++) emb[i] = (const float*)d_in[i];
    const float* embAll = (const float*)d_in[4];
    const float* Wq[4];
    for (int i = 0; i < 4; i++) Wq[i] = (const float*)d_in[5 + i];
    const float* Wk = (const float*)d_in[9];
    const float* Wv = (const float*)d_in[10];
    const float* Wo[4];
    for (int i = 0; i < 4; i++) Wo[i] = (const float*)d_in[11 + i];
    float* out = (float*)d_out;
    size_t outOff[4];
    {
        size_t o = 0;
        for (int i = 0; i < 4; i++) { outOff[i] = o; o += (size_t)B * NN * Cs[i]; }
    }

    const size_t SKV = 62914560;
    const size_t SSC = 58982400;
    const size_t SWQ = 2785280, SWO = 696320, SCM = 8388608;
    const size_t SPART = 131072, SST = 1024;
    const size_t SMALL = SWQ + SWO + SCM + SPART + SST;
    const size_t NEED_BAT = SSC + 3 * SKV + SMALL + 512;

    float invs = 1.0f / sqrtf((float)KV);
    auto g128 = [](int n) { return (n + 127) / 128; };

    if (ws_size >= NEED_BAT) {
        // ================= batched path =================
        char* p = (char*)d_ws;
        u16* scB = (u16*)p;        p += SSC;
        u16* QtB = (u16*)p;        p += SKV;
        u16* Kt = (u16*)p;         p += SKV;
        u16* VbC = (u16*)p;        p += SKV;
        u16* wq[4];
        for (int i = 0; i < 4; i++) { wq[i] = (u16*)p; p += (size_t)4 * Cs[i] * Cs[i] * 2; }
        u16* wo[4];
        for (int i = 0; i < 4; i++) { wo[i] = (u16*)p; p += (size_t)Cs[i] * Cs[i] * 2; }
        u16* cmX = (u16*)p;        p += SCM;
        double* part = (double*)p; p += SPART;
        (void)cmX;

        u16* eA = scB;
        u16* wk = (u16*)((char*)scB + 15728640);
        u16* wv = (u16*)((char*)scB + 23101440);
        u16* embB[4];
        {
            size_t eo = 30474240 / 2;
            for (int i = 0; i < 4; i++) {
                embB[i] = scB + eo;
                eo += (size_t)B * NN * Cs[i];
            }
        }
        u16* prB = QtB;
        u16* cmC = scB;

        // ---- single mega-cast: 15 segments ----
        {
            CastPack cp;
            int ns = 0;
            auto add = [&](const float* s, u16* d, size_t n) {
                cp.src[ns] = (const float4*)s;
                cp.dst[ns] = (u16x4*)d;
                cp.n4[ns] = (int)(n / 4);
                ns++;
            };
            add(embAll, eA, (size_t)B * NN * KV);
            add(Wk, wk, (size_t)4 * KV * KV);
            add(Wv, wv, (size_t)4 * KV * KV);
            for (int i = 0; i < 4; i++) add(Wq[i], wq[i], (size_t)4 * Cs[i] * Cs[i]);
            for (int i = 0; i < 4; i++) add(Wo[i], wo[i], (size_t)Cs[i] * Cs[i]);
            for (int i = 0; i < 4; i++) add(emb[i], embB[i], (size_t)B * NN * Cs[i]);
            cp.nseg = ns;
            cp.cum[0] = 0;
            for (int i = 0; i < ns; i++) {
                int nb = (cp.n4[i] + 1023) / 1024;
                if (nb < 1) nb = 1;
                cp.cum[i + 1] = cp.cum[i] + nb;
            }
            cast_multi<<<cp.cum[ns], 256, 0, stream>>>(cp);
        }

        // Kt[z][j][n]
        gemm_nt_4ph<256><<<dim3(4, 4, 32), 512, 0, stream>>>(
            wk, 0, (long)KV * KV, KV, eA, (long)NN * KV, 0, KV,
            Kt, 4 * 983040L, 983040L, NN, KV, NN, KV, 4, 1.0f);
        // VbCat[b][n][h*960+j]
        gemm_nt_4ph<256><<<dim3(4, 4, 32), 512, 0, stream>>>(
            eA, (long)NN * KV, 0, KV, wv, 0, (long)KV * KV, KV,
            VbC, (long)NN * 3840, 960L, 3840, NN, KV, KV, 4, 1.0f);

        // Q-proj C=512 on 4ph
        gemm_nt_4ph<256><<<dim3(4, 2, 32), 512, 0, stream>>>(
            wq[3], 0, 512L * 512, 512, embB[3], (long)NN * 512, 0, 512,
            QtB, 4 * 983040L, 983040L, NN, 512, NN, 512, 4, 1.0f);
        // Q-proj C in {64,128,256}: one grouped launch
        {
            GPack gp;
            gp.nseg = 3;
            gp.cum[0] = 0;
            for (int i = 0; i < 3; i++) {
                int C = Cs[i];
                GSeg& g = gp.s[i];
                g.A = wq[i]; g.sAb = 0; g.sAh = (long)C * C; g.lda = C;
                g.B = embB[i]; g.sBb = (long)NN * C; g.sBh = 0; g.ldb = C;
                g.Cp = (void*)(QtB + (size_t)offsIn[i] * 1024);
                g.sCb = 4 * 983040L; g.sCh = 983040L; g.ldc = NN;
                g.M = C; g.N = NN; g.K = C; g.hdiv = 4;
                g.gx = 8; g.gy = g128(C); g.isF32 = 0; g.alpha = 1.0f;
                gp.cum[i + 1] = gp.cum[i] + g.gx * g.gy * 32;
            }
            gemm_nt128_grp<<<gp.cum[3], 256, 0, stream>>>(gp);
        }
        // one big QK: scB[z][960 c][960 k] bf16
        gemm_nt_4ph<256><<<dim3(4, 4, 32), 512, 0, stream>>>(
            QtB, 983040L, 0, NN, Kt, 983040L, 0, NN,
            scB, 921600L, 0, KV, 960, KV, NN, 1, invs);
        // instance-norm stats (128 planes) + softmax (stats2 fused) -> prCat
        in_stats1<<<dim3(16, 128), 256, 0, stream>>>(scB, part, 16, 1, 0);
        norm_softmax_cat2<<<32 * 960, 256, 0, stream>>>(scB, part, prB);
        // fused PV + head-mean
        gemm_nt_4ph<128><<<dim3(4, 8, 8), 512, 0, stream>>>(
            VbC, (long)NN * 3840, 0, 3840, prB, (long)960 * 3840, 0, 3840,
            cmC, (long)NN * 960, 0, 960, NN, 960, 3840, 1, 0.25f);
        // out-proj: all 4 branches in one grouped launch (f32 epilogue)
        {
            GPack gp;
            gp.nseg = 4;
            gp.cum[0] = 0;
            for (int i = 0; i < 4; i++) {
                int C = Cs[i];
                GSeg& g = gp.s[i];
                g.A = cmC + offsIn[i]; g.sAb = (long)NN * 960; g.sAh = 0; g.lda = 960;
                g.B = wo[i]; g.sBb = 0; g.sBh = 0; g.ldb = C;
                g.Cp = (void*)(out + outOff[i]);
                g.sCb = (long)NN * C; g.sCh = 0; g.ldc = C;
                g.M = NN; g.N = C; g.K = C; g.hdiv = 1;
                g.gx = g128(C); g.gy = 8; g.isF32 = 1; g.alpha = 1.0f;
                gp.cum[i + 1] = gp.cum[i] + g.gx * g.gy * 8;
            }
            gemm_nt128_grp<<<gp.cum[4], 256, 0, stream>>>(gp);
        }
    } else {
        // ================= fallback per-branch path (~205 MB) =================
        const size_t S1 = 33554432, S2 = 33554432;
        if (ws_size < S1 + S2 + 2 * SKV + SMALL + 512) return;
        char* p = (char*)d_ws;
        char* buf1 = p;            p += S1;
        char* buf2 = p;            p += S2;
        u16* Kt = (u16*)p;         p += SKV;
        u16* Vb = (u16*)p;         p += SKV;
        u16* wq[4];
        for (int i = 0; i < 4; i++) { wq[i] = (u16*)p; p += (size_t)4 * Cs[i] * Cs[i] * 2; }
        u16* wo[4];
        for (int i = 0; i < 4; i++) { wo[i] = (u16*)p; p += (size_t)Cs[i] * Cs[i] * 2; }
        u16* cmX = (u16*)p;        p += SCM;
        double* part = (double*)p; p += SPART;
        float* stats = (float*)p;

        u16* eA = (u16*)buf1;
        u16* wk = (u16*)(buf1 + 15728640);
        u16* wv = (u16*)(buf1 + 23101440);
        u16* sc = (u16*)buf1;
        u16* Qt = (u16*)buf2;
        u16* ctx = (u16*)buf2;

        auto castL = [&](const float* s, u16* d, size_t n) {
            int n4 = (int)(n / 4);
            cast_bf16<<<(n4 + 255) / 256, 256, 0, stream>>>((const float4*)s, (u16x4*)d, n4);
        };
        castL(embAll, eA, (size_t)B * NN * KV);
        castL(Wk, wk, (size_t)4 * KV * KV);
        castL(Wv, wv, (size_t)4 * KV * KV);
        for (int i = 0; i < 4; i++) castL(Wq[i], wq[i], (size_t)4 * Cs[i] * Cs[i]);
        for (int i = 0; i < 4; i++) castL(Wo[i], wo[i], (size_t)Cs[i] * Cs[i]);

        gemm_nt128<u16><<<dim3(8, 8, 32), 256, 0, stream>>>(
            wk, 0, (long)KV * KV, KV, eA, (long)NN * KV, 0, KV,
            Kt, 4 * 983040L, 983040L, NN, KV, NN, KV, 4, 1.0f);
        gemm_nt128<u16><<<dim3(8, 8, 32), 256, 0, stream>>>(
            eA, (long)NN * KV, 0, KV, wv, 0, (long)KV * KV, KV,
            Vb, 4 * 983040L, 983040L, KV, NN, KV, KV, 4, 1.0f);

        for (int i = 0; i < 4; i++) {
            int C = Cs[i];
            castL(emb[i], cmX, (size_t)B * NN * C);
            gemm_nt128<u16><<<dim3(8, g128(C), 32), 256, 0, stream>>>(
                wq[i], 0, (long)C * C, C, cmX, (long)NN * C, 0, C,
                Qt, 4L * C * NN, (long)C * NN, NN, C, NN, C, 4, 1.0f);
            gemm_nt128<u16><<<dim3(8, g128(C), 32), 256, 0, stream>>>(
                Qt, (long)C * NN, 0, NN, Kt, 983040L, 0, NN,
                sc, (long)C * KV, 0, KV, C, KV, NN, 1, invs);
            in_stats1<<<dim3(64, 32), 256, 0, stream>>>(sc, part, 64, 0, C);
            in_stats2<<<32, 64, 0, stream>>>(part, stats, 64, 0, C);
            norm_softmax_ip<<<32 * C, 256, 0, stream>>>(sc, stats, C);
            gemm_nt128<u16><<<dim3(8, g128(C), 32), 256, 0, stream>>>(
                sc, (long)C * KV, 0, KV, Vb, 983040L, 0, KV,
                ctx, (long)C * NN, 0, NN, C, NN, KV, 1, 1.0f);
            mean_heads<<<dim3(16, C / 64, B), 256, 0, stream>>>(
                ctx, (long)C * NN, cmX, C);
            gemm_nt128<float><<<dim3(g128(C), 8, B), 256, 0, stream>>>(
                cmX, (long)NN * C, 0, C, wo[i], 0, 0, C,
                out + outOff[i], (long)NN * C, 0, C, NN, C, C, 1, 1.0f);
        }
    }
}